// Round 1
// baseline (1575.837 us; speedup 1.0000x reference)
//
#include <hip/hip_runtime.h>

#define N_NODES 1000000
#define N_EDGES 32000000

// ---------------------------------------------------------------------------
// Kernel 1: zero the aggregation buffer (4 MB).
// ---------------------------------------------------------------------------
__global__ void gin_zero_kernel(float* __restrict__ agg, int n) {
    int i = blockIdx.x * blockDim.x + threadIdx.x;
    if (i < n) agg[i] = 0.0f;
}

// ---------------------------------------------------------------------------
// Kernel 2: edge scatter-add.  agg[dst[e]] += x[src[e]] for all edges.
// src/dst are each 32M int32; loaded as int4 (4 edges per thread).
// x (4 MB) and agg (4 MB) are cache-resident; edge_index stream dominates.
// ---------------------------------------------------------------------------
__global__ void gin_scatter_kernel(const float* __restrict__ x,
                                   const int* __restrict__ src,
                                   const int* __restrict__ dst,
                                   float* __restrict__ agg) {
    int q = blockIdx.x * blockDim.x + threadIdx.x;   // quad index
    int e = q * 4;
    if (e + 3 < N_EDGES) {
        int4 s = *reinterpret_cast<const int4*>(src + e);
        int4 d = *reinterpret_cast<const int4*>(dst + e);
        float xs0 = x[s.x];
        float xs1 = x[s.y];
        float xs2 = x[s.z];
        float xs3 = x[s.w];
        atomicAdd(&agg[d.x], xs0);
        atomicAdd(&agg[d.y], xs1);
        atomicAdd(&agg[d.z], xs2);
        atomicAdd(&agg[d.w], xs3);
    } else if (e < N_EDGES) {
        for (; e < N_EDGES; ++e) atomicAdd(&agg[dst[e]], x[src[e]]);
    }
}

// ---------------------------------------------------------------------------
// Kernel 3: fused GIN epilogue + MLP.  One thread per node.
//   h0 = (1+eps)*x[i] + agg[i]
//   h1 = relu(h0*w1 + b1)            [20]
//   h2 = relu(h1@w2 + b2)            [20]
//   out = h2@w3 + b3                 [1]
// Weight reads are wave-uniform -> scalar loads / L1 broadcast.
// ---------------------------------------------------------------------------
__global__ void gin_mlp_kernel(const float* __restrict__ x,
                               const float* __restrict__ agg,
                               const float* __restrict__ eps,
                               const float* __restrict__ w1,
                               const float* __restrict__ b1,
                               const float* __restrict__ w2,
                               const float* __restrict__ b2,
                               const float* __restrict__ w3,
                               const float* __restrict__ b3,
                               float* __restrict__ out) {
    int i = blockIdx.x * blockDim.x + threadIdx.x;
    if (i >= N_NODES) return;

    float h0 = (1.0f + eps[0]) * x[i] + agg[i];

    float h1[20];
#pragma unroll
    for (int j = 0; j < 20; ++j) {
        h1[j] = fmaxf(fmaf(h0, w1[j], b1[j]), 0.0f);
    }

    float o = b3[0];
#pragma unroll
    for (int k = 0; k < 20; ++k) {
        float acc = b2[k];
#pragma unroll
        for (int j = 0; j < 20; ++j) {
            acc = fmaf(h1[j], w2[j * 20 + k], acc);
        }
        o = fmaf(fmaxf(acc, 0.0f), w3[k], o);
    }
    out[i] = o;
}

// ---------------------------------------------------------------------------
extern "C" void kernel_launch(void* const* d_in, const int* in_sizes, int n_in,
                              void* d_out, int out_size, void* d_ws, size_t ws_size,
                              hipStream_t stream) {
    const float* x    = (const float*)d_in[0];
    const int*   ei   = (const int*)  d_in[1];   // [2, N_EDGES], int32 per harness contract
    const float* eps  = (const float*)d_in[2];
    const float* w1   = (const float*)d_in[3];
    const float* b1   = (const float*)d_in[4];
    const float* w2   = (const float*)d_in[5];
    const float* b2   = (const float*)d_in[6];
    const float* w3   = (const float*)d_in[7];
    const float* b3   = (const float*)d_in[8];
    float* out = (float*)d_out;

    const int* src = ei;
    const int* dst = ei + N_EDGES;

    // agg buffer: use workspace if big enough, else alias d_out (safe:
    // MLP kernel thread i reads agg[i] then writes out[i], no cross-thread).
    float* agg = (ws_size >= (size_t)N_NODES * sizeof(float)) ? (float*)d_ws : out;

    {
        int threads = 256;
        int blocks = (N_NODES + threads - 1) / threads;
        gin_zero_kernel<<<blocks, threads, 0, stream>>>(agg, N_NODES);
    }
    {
        int threads = 256;
        int quads = N_EDGES / 4;  // 32M divisible by 4
        int blocks = (quads + threads - 1) / threads;
        gin_scatter_kernel<<<blocks, threads, 0, stream>>>(x, src, dst, agg);
    }
    {
        int threads = 256;
        int blocks = (N_NODES + threads - 1) / threads;
        gin_mlp_kernel<<<blocks, threads, 0, stream>>>(x, agg, eps, w1, b1, w2, b2,
                                                       w3, b3, out);
    }
}

// Round 2
// 885.474 us; speedup vs baseline: 1.7797x; 1.7797x over previous
//
#include <hip/hip_runtime.h>

#define N_NODES 1000000
#define N_EDGES 32000000

// ---- binning configuration -------------------------------------------------
#define NB      2000      // blocks for count/scatter phases
#define EPB     16000     // edges per block (NB * EPB == N_EDGES)
#define QPB     4000      // int4 quads per block
#define NBUCKET 977       // ceil(1e6 / 1024); bucket = dst >> 10
#define BPAD    1024      // padded bucket count for LDS/global arrays
#define CAP     34816     // per-bucket capacity (mean 32753, +11 sigma)

// ws layout
#define BINS_ELEMS  ((size_t)NBUCKET * CAP)                 // 34,015,232 u32
#define CNT_ELEMS   ((size_t)NB * BPAD)                     // 2,048,000 u32
#define WS_NEEDED   ((BINS_ELEMS + CNT_ELEMS + BPAD) * 4)   // ~144.3 MB

// ---------------------------------------------------------------------------
// P1: per-(block,bucket) histogram of dst.
// ---------------------------------------------------------------------------
__global__ void gin_count(const int* __restrict__ dst, unsigned* __restrict__ cnt) {
    __shared__ unsigned h[BPAD];
    int tid = threadIdx.x;
    for (int i = tid; i < BPAD; i += 256) h[i] = 0u;
    __syncthreads();
    int k = blockIdx.x;
    const int4* q = reinterpret_cast<const int4*>(dst) + (size_t)k * QPB;
    for (int i = tid; i < QPB; i += 256) {
        int4 d = q[i];
        atomicAdd(&h[d.x >> 10], 1u);
        atomicAdd(&h[d.y >> 10], 1u);
        atomicAdd(&h[d.z >> 10], 1u);
        atomicAdd(&h[d.w >> 10], 1u);
    }
    __syncthreads();
    for (int i = tid; i < BPAD; i += 256) cnt[(size_t)k * BPAD + i] = h[i];
}

// ---------------------------------------------------------------------------
// P2: one wave per bucket: exclusive scan of cnt[k][b] over k, total -> tot[b].
// ---------------------------------------------------------------------------
__global__ void gin_scan(unsigned* __restrict__ cnt, unsigned* __restrict__ tot) {
    int gtid = blockIdx.x * blockDim.x + threadIdx.x;
    int b = gtid >> 6;          // wave id = bucket
    int lane = gtid & 63;
    if (b >= BPAD) return;
    unsigned running = 0;
    for (int base = 0; base < NB; base += 64) {
        int idx = base + lane;
        unsigned v = (idx < NB) ? cnt[(size_t)idx * BPAD + b] : 0u;
        unsigned s = v;
        for (int d = 1; d < 64; d <<= 1) {
            unsigned u = __shfl_up(s, d);
            if (lane >= d) s += u;
        }
        unsigned excl = s - v;
        if (idx < NB) cnt[(size_t)idx * BPAD + b] = running + excl;
        running += __shfl(s, 63);
    }
    if (lane == 0) tot[b] = running;
}

// ---------------------------------------------------------------------------
// P3: scatter edges into dense per-bucket bins. Packed entry:
//     (dst & 1023) << 20 | src     (src < 2^20).  LDS atomics only.
// ---------------------------------------------------------------------------
__global__ void gin_scatter_bins(const int* __restrict__ src,
                                 const int* __restrict__ dst,
                                 const unsigned* __restrict__ cnt,
                                 unsigned* __restrict__ bins) {
    __shared__ unsigned run[BPAD];
    int tid = threadIdx.x;
    int k = blockIdx.x;
    for (int i = tid; i < BPAD; i += 256) run[i] = cnt[(size_t)k * BPAD + i];
    __syncthreads();
    const int4* qs = reinterpret_cast<const int4*>(src) + (size_t)k * QPB;
    const int4* qd = reinterpret_cast<const int4*>(dst) + (size_t)k * QPB;
    for (int i = tid; i < QPB; i += 256) {
        int4 s4 = qs[i];
        int4 d4 = qd[i];
        {
            int b = d4.x >> 10; unsigned dl = (unsigned)(d4.x & 1023);
            unsigned p = atomicAdd(&run[b], 1u);
            if (p < CAP) bins[(size_t)b * CAP + p] = (dl << 20) | (unsigned)s4.x;
        }
        {
            int b = d4.y >> 10; unsigned dl = (unsigned)(d4.y & 1023);
            unsigned p = atomicAdd(&run[b], 1u);
            if (p < CAP) bins[(size_t)b * CAP + p] = (dl << 20) | (unsigned)s4.y;
        }
        {
            int b = d4.z >> 10; unsigned dl = (unsigned)(d4.z & 1023);
            unsigned p = atomicAdd(&run[b], 1u);
            if (p < CAP) bins[(size_t)b * CAP + p] = (dl << 20) | (unsigned)s4.z;
        }
        {
            int b = d4.w >> 10; unsigned dl = (unsigned)(d4.w & 1023);
            unsigned p = atomicAdd(&run[b], 1u);
            if (p < CAP) bins[(size_t)b * CAP + p] = (dl << 20) | (unsigned)s4.w;
        }
    }
}

// ---------------------------------------------------------------------------
// P4: per-bucket reduce (LDS fp32 atomics) + fused MLP + store.
// ---------------------------------------------------------------------------
__global__ void gin_reduce_mlp(const unsigned* __restrict__ bins,
                               const unsigned* __restrict__ tot,
                               const float* __restrict__ x,
                               const float* __restrict__ eps,
                               const float* __restrict__ w1,
                               const float* __restrict__ b1,
                               const float* __restrict__ w2,
                               const float* __restrict__ b2,
                               const float* __restrict__ w3,
                               const float* __restrict__ b3,
                               float* __restrict__ out) {
    __shared__ float acc[1024];
    int tid = threadIdx.x;
    int b = blockIdx.x;                    // 0..NBUCKET-1
    for (int i = tid; i < 1024; i += 256) acc[i] = 0.0f;
    __syncthreads();

    unsigned n = tot[b];
    if (n > CAP) n = CAP;
    const unsigned* bb = bins + (size_t)b * CAP;
    for (unsigned i = tid; i < n; i += 256) {
        unsigned e = bb[i];
        unsigned srcn = e & 0xFFFFFu;
        unsigned dl = e >> 20;
        atomicAdd(&acc[dl], x[srcn]);      // LDS atomic
    }
    __syncthreads();

    float epsv = 1.0f + eps[0];
    for (int j = tid; j < 1024; j += 256) {
        int node = (b << 10) + j;
        if (node >= N_NODES) break;
        float h0 = epsv * x[node] + acc[j];

        float h1[20];
#pragma unroll
        for (int jj = 0; jj < 20; ++jj)
            h1[jj] = fmaxf(fmaf(h0, w1[jj], b1[jj]), 0.0f);

        float o = b3[0];
#pragma unroll
        for (int k = 0; k < 20; ++k) {
            float a = b2[k];
#pragma unroll
            for (int jj = 0; jj < 20; ++jj)
                a = fmaf(h1[jj], w2[jj * 20 + k], a);
            o = fmaf(fmaxf(a, 0.0f), w3[k], o);
        }
        out[node] = o;
    }
}

// ---------------------------------------------------------------------------
// Fallback path (round-1 kernels) if ws is too small for binning.
// ---------------------------------------------------------------------------
__global__ void gin_zero_kernel(float* __restrict__ agg, int n) {
    int i = blockIdx.x * blockDim.x + threadIdx.x;
    if (i < n) agg[i] = 0.0f;
}

__global__ void gin_scatter_kernel(const float* __restrict__ x,
                                   const int* __restrict__ src,
                                   const int* __restrict__ dst,
                                   float* __restrict__ agg) {
    int q = blockIdx.x * blockDim.x + threadIdx.x;
    int e = q * 4;
    if (e + 3 < N_EDGES) {
        int4 s = *reinterpret_cast<const int4*>(src + e);
        int4 d = *reinterpret_cast<const int4*>(dst + e);
        atomicAdd(&agg[d.x], x[s.x]);
        atomicAdd(&agg[d.y], x[s.y]);
        atomicAdd(&agg[d.z], x[s.z]);
        atomicAdd(&agg[d.w], x[s.w]);
    } else if (e < N_EDGES) {
        for (; e < N_EDGES; ++e) atomicAdd(&agg[dst[e]], x[src[e]]);
    }
}

__global__ void gin_mlp_kernel(const float* __restrict__ x,
                               const float* __restrict__ agg,
                               const float* __restrict__ eps,
                               const float* __restrict__ w1,
                               const float* __restrict__ b1,
                               const float* __restrict__ w2,
                               const float* __restrict__ b2,
                               const float* __restrict__ w3,
                               const float* __restrict__ b3,
                               float* __restrict__ out) {
    int i = blockIdx.x * blockDim.x + threadIdx.x;
    if (i >= N_NODES) return;
    float h0 = (1.0f + eps[0]) * x[i] + agg[i];
    float h1[20];
#pragma unroll
    for (int j = 0; j < 20; ++j) h1[j] = fmaxf(fmaf(h0, w1[j], b1[j]), 0.0f);
    float o = b3[0];
#pragma unroll
    for (int k = 0; k < 20; ++k) {
        float a = b2[k];
#pragma unroll
        for (int j = 0; j < 20; ++j) a = fmaf(h1[j], w2[j * 20 + k], a);
        o = fmaf(fmaxf(a, 0.0f), w3[k], o);
    }
    out[i] = o;
}

// ---------------------------------------------------------------------------
extern "C" void kernel_launch(void* const* d_in, const int* in_sizes, int n_in,
                              void* d_out, int out_size, void* d_ws, size_t ws_size,
                              hipStream_t stream) {
    const float* x    = (const float*)d_in[0];
    const int*   ei   = (const int*)  d_in[1];
    const float* eps  = (const float*)d_in[2];
    const float* w1   = (const float*)d_in[3];
    const float* b1   = (const float*)d_in[4];
    const float* w2   = (const float*)d_in[5];
    const float* b2   = (const float*)d_in[6];
    const float* w3   = (const float*)d_in[7];
    const float* b3   = (const float*)d_in[8];
    float* out = (float*)d_out;

    const int* src = ei;
    const int* dst = ei + N_EDGES;

    if (ws_size >= WS_NEEDED) {
        unsigned* bins = (unsigned*)d_ws;
        unsigned* cnt  = bins + BINS_ELEMS;
        unsigned* tot  = cnt + CNT_ELEMS;

        gin_count<<<NB, 256, 0, stream>>>(dst, cnt);
        {
            int waves_needed = BPAD;                       // covers 977, pads harmless
            int blocks = (waves_needed * 64 + 255) / 256;  // 256 blocks
            gin_scan<<<blocks, 256, 0, stream>>>(cnt, tot);
        }
        gin_scatter_bins<<<NB, 256, 0, stream>>>(src, dst, cnt, bins);
        gin_reduce_mlp<<<NBUCKET, 256, 0, stream>>>(bins, tot, x, eps,
                                                    w1, b1, w2, b2, w3, b3, out);
    } else {
        // fallback: global-atomic path
        float* agg = (ws_size >= (size_t)N_NODES * sizeof(float)) ? (float*)d_ws : out;
        {
            int blocks = (N_NODES + 255) / 256;
            gin_zero_kernel<<<blocks, 256, 0, stream>>>(agg, N_NODES);
        }
        {
            int quads = N_EDGES / 4;
            int blocks = (quads + 255) / 256;
            gin_scatter_kernel<<<blocks, 256, 0, stream>>>(x, src, dst, agg);
        }
        {
            int blocks = (N_NODES + 255) / 256;
            gin_mlp_kernel<<<blocks, 256, 0, stream>>>(x, agg, eps, w1, b1, w2, b2,
                                                       w3, b3, out);
        }
    }
}

// Round 3
// 696.035 us; speedup vs baseline: 2.2640x; 1.2722x over previous
//
#include <hip/hip_runtime.h>

#define N_NODES 1000000
#define N_EDGES 32000000

// ---- binning configuration -------------------------------------------------
// Scatter grid sized so all per-bucket frontier lines stay L2-resident:
// 256 blocks -> 32 resident blocks/XCD x 977 frontier lines x 64B ~= 2.0 MB < 4 MB L2.
#define NB        256       // blocks for count/scatter phases
#define THREADS_SC 512      // threads per count/scatter block
#define EPB       125000    // edges per block (NB * EPB == N_EDGES)
#define QPB       31250     // int4 quads per block
#define NBUCKET   977       // ceil(1e6 / 1024); bucket = dst >> 10
#define BPAD      1024      // padded bucket count
#define CAP       34816     // per-bucket capacity (mean 32753, +11 sigma)

#define BINS_ELEMS  ((size_t)NBUCKET * CAP)                 // 34,015,232 u32
#define CNT_ELEMS   ((size_t)NB * BPAD)                     // 262,144 u32
#define WS_NEEDED   ((BINS_ELEMS + CNT_ELEMS + BPAD) * 4)   // ~137 MB

// ---------------------------------------------------------------------------
// P1: per-(block,bucket) histogram of dst.
// ---------------------------------------------------------------------------
__global__ void gin_count(const int* __restrict__ dst, unsigned* __restrict__ cnt) {
    __shared__ unsigned h[BPAD];
    int tid = threadIdx.x;
    for (int i = tid; i < BPAD; i += THREADS_SC) h[i] = 0u;
    __syncthreads();
    int k = blockIdx.x;
    const int4* q = reinterpret_cast<const int4*>(dst) + (size_t)k * QPB;
    for (int i = tid; i < QPB; i += THREADS_SC) {
        int4 d = q[i];
        atomicAdd(&h[d.x >> 10], 1u);
        atomicAdd(&h[d.y >> 10], 1u);
        atomicAdd(&h[d.z >> 10], 1u);
        atomicAdd(&h[d.w >> 10], 1u);
    }
    __syncthreads();
    for (int i = tid; i < BPAD; i += THREADS_SC) cnt[(size_t)k * BPAD + i] = h[i];
}

// ---------------------------------------------------------------------------
// P2: one wave per bucket: exclusive scan of cnt[k][b] over k, total -> tot[b].
// ---------------------------------------------------------------------------
__global__ void gin_scan(unsigned* __restrict__ cnt, unsigned* __restrict__ tot) {
    int gtid = blockIdx.x * blockDim.x + threadIdx.x;
    int b = gtid >> 6;          // wave id = bucket
    int lane = gtid & 63;
    if (b >= BPAD) return;
    unsigned running = 0;
    for (int base = 0; base < NB; base += 64) {
        int idx = base + lane;
        unsigned v = (idx < NB) ? cnt[(size_t)idx * BPAD + b] : 0u;
        unsigned s = v;
        for (int d = 1; d < 64; d <<= 1) {
            unsigned u = __shfl_up(s, d);
            if (lane >= d) s += u;
        }
        unsigned excl = s - v;
        if (idx < NB) cnt[(size_t)idx * BPAD + b] = running + excl;
        running += __shfl(s, 63);
    }
    if (lane == 0) tot[b] = running;
}

// ---------------------------------------------------------------------------
// P3: scatter edges into dense per-bucket bins. Packed entry:
//     (dst & 1023) << 20 | src     (src < 2^20).  LDS atomics only.
// ---------------------------------------------------------------------------
__global__ void gin_scatter_bins(const int* __restrict__ src,
                                 const int* __restrict__ dst,
                                 const unsigned* __restrict__ cnt,
                                 unsigned* __restrict__ bins) {
    __shared__ unsigned run[BPAD];
    int tid = threadIdx.x;
    int k = blockIdx.x;
    for (int i = tid; i < BPAD; i += THREADS_SC) run[i] = cnt[(size_t)k * BPAD + i];
    __syncthreads();
    const int4* qs = reinterpret_cast<const int4*>(src) + (size_t)k * QPB;
    const int4* qd = reinterpret_cast<const int4*>(dst) + (size_t)k * QPB;
    for (int i = tid; i < QPB; i += THREADS_SC) {
        int4 s4 = qs[i];
        int4 d4 = qd[i];
        {
            int b = d4.x >> 10; unsigned dl = (unsigned)(d4.x & 1023);
            unsigned p = atomicAdd(&run[b], 1u);
            if (p < CAP) bins[(size_t)b * CAP + p] = (dl << 20) | (unsigned)s4.x;
        }
        {
            int b = d4.y >> 10; unsigned dl = (unsigned)(d4.y & 1023);
            unsigned p = atomicAdd(&run[b], 1u);
            if (p < CAP) bins[(size_t)b * CAP + p] = (dl << 20) | (unsigned)s4.y;
        }
        {
            int b = d4.z >> 10; unsigned dl = (unsigned)(d4.z & 1023);
            unsigned p = atomicAdd(&run[b], 1u);
            if (p < CAP) bins[(size_t)b * CAP + p] = (dl << 20) | (unsigned)s4.z;
        }
        {
            int b = d4.w >> 10; unsigned dl = (unsigned)(d4.w & 1023);
            unsigned p = atomicAdd(&run[b], 1u);
            if (p < CAP) bins[(size_t)b * CAP + p] = (dl << 20) | (unsigned)s4.w;
        }
    }
}

// ---------------------------------------------------------------------------
// P4: per-bucket reduce (LDS fp32 atomics) + fused MLP + store.
// ---------------------------------------------------------------------------
__global__ void gin_reduce_mlp(const unsigned* __restrict__ bins,
                               const unsigned* __restrict__ tot,
                               const float* __restrict__ x,
                               const float* __restrict__ eps,
                               const float* __restrict__ w1,
                               const float* __restrict__ b1,
                               const float* __restrict__ w2,
                               const float* __restrict__ b2,
                               const float* __restrict__ w3,
                               const float* __restrict__ b3,
                               float* __restrict__ out) {
    __shared__ float acc[1024];
    int tid = threadIdx.x;
    int b = blockIdx.x;                    // 0..NBUCKET-1
    for (int i = tid; i < 1024; i += 256) acc[i] = 0.0f;
    __syncthreads();

    unsigned n = tot[b];
    if (n > CAP) n = CAP;
    const unsigned* bb = bins + (size_t)b * CAP;
    const uint4* bb4 = reinterpret_cast<const uint4*>(bb);   // CAP*4 % 16 == 0
    unsigned nq = n >> 2;
    for (unsigned i = tid; i < nq; i += 256) {
        uint4 e = bb4[i];
        atomicAdd(&acc[e.x >> 20], x[e.x & 0xFFFFFu]);
        atomicAdd(&acc[e.y >> 20], x[e.y & 0xFFFFFu]);
        atomicAdd(&acc[e.z >> 20], x[e.z & 0xFFFFFu]);
        atomicAdd(&acc[e.w >> 20], x[e.w & 0xFFFFFu]);
    }
    for (unsigned i = (nq << 2) + tid; i < n; i += 256) {
        unsigned e = bb[i];
        atomicAdd(&acc[e >> 20], x[e & 0xFFFFFu]);
    }
    __syncthreads();

    float epsv = 1.0f + eps[0];
    for (int j = tid; j < 1024; j += 256) {
        int node = (b << 10) + j;
        if (node >= N_NODES) break;
        float h0 = epsv * x[node] + acc[j];

        float h1[20];
#pragma unroll
        for (int jj = 0; jj < 20; ++jj)
            h1[jj] = fmaxf(fmaf(h0, w1[jj], b1[jj]), 0.0f);

        float o = b3[0];
#pragma unroll
        for (int k = 0; k < 20; ++k) {
            float a = b2[k];
#pragma unroll
            for (int jj = 0; jj < 20; ++jj)
                a = fmaf(h1[jj], w2[jj * 20 + k], a);
            o = fmaf(fmaxf(a, 0.0f), w3[k], o);
        }
        out[node] = o;
    }
}

// ---------------------------------------------------------------------------
// Fallback path (round-1 kernels) if ws is too small for binning.
// ---------------------------------------------------------------------------
__global__ void gin_zero_kernel(float* __restrict__ agg, int n) {
    int i = blockIdx.x * blockDim.x + threadIdx.x;
    if (i < n) agg[i] = 0.0f;
}

__global__ void gin_scatter_kernel(const float* __restrict__ x,
                                   const int* __restrict__ src,
                                   const int* __restrict__ dst,
                                   float* __restrict__ agg) {
    int q = blockIdx.x * blockDim.x + threadIdx.x;
    int e = q * 4;
    if (e + 3 < N_EDGES) {
        int4 s = *reinterpret_cast<const int4*>(src + e);
        int4 d = *reinterpret_cast<const int4*>(dst + e);
        atomicAdd(&agg[d.x], x[s.x]);
        atomicAdd(&agg[d.y], x[s.y]);
        atomicAdd(&agg[d.z], x[s.z]);
        atomicAdd(&agg[d.w], x[s.w]);
    } else if (e < N_EDGES) {
        for (; e < N_EDGES; ++e) atomicAdd(&agg[dst[e]], x[src[e]]);
    }
}

__global__ void gin_mlp_kernel(const float* __restrict__ x,
                               const float* __restrict__ agg,
                               const float* __restrict__ eps,
                               const float* __restrict__ w1,
                               const float* __restrict__ b1,
                               const float* __restrict__ w2,
                               const float* __restrict__ b2,
                               const float* __restrict__ w3,
                               const float* __restrict__ b3,
                               float* __restrict__ out) {
    int i = blockIdx.x * blockDim.x + threadIdx.x;
    if (i >= N_NODES) return;
    float h0 = (1.0f + eps[0]) * x[i] + agg[i];
    float h1[20];
#pragma unroll
    for (int j = 0; j < 20; ++j) h1[j] = fmaxf(fmaf(h0, w1[j], b1[j]), 0.0f);
    float o = b3[0];
#pragma unroll
    for (int k = 0; k < 20; ++k) {
        float a = b2[k];
#pragma unroll
        for (int j = 0; j < 20; ++j) a = fmaf(h1[j], w2[j * 20 + k], a);
        o = fmaf(fmaxf(a, 0.0f), w3[k], o);
    }
    out[i] = o;
}

// ---------------------------------------------------------------------------
extern "C" void kernel_launch(void* const* d_in, const int* in_sizes, int n_in,
                              void* d_out, int out_size, void* d_ws, size_t ws_size,
                              hipStream_t stream) {
    const float* x    = (const float*)d_in[0];
    const int*   ei   = (const int*)  d_in[1];
    const float* eps  = (const float*)d_in[2];
    const float* w1   = (const float*)d_in[3];
    const float* b1   = (const float*)d_in[4];
    const float* w2   = (const float*)d_in[5];
    const float* b2   = (const float*)d_in[6];
    const float* w3   = (const float*)d_in[7];
    const float* b3   = (const float*)d_in[8];
    float* out = (float*)d_out;

    const int* src = ei;
    const int* dst = ei + N_EDGES;

    if (ws_size >= WS_NEEDED) {
        unsigned* bins = (unsigned*)d_ws;
        unsigned* cnt  = bins + BINS_ELEMS;
        unsigned* tot  = cnt + CNT_ELEMS;

        gin_count<<<NB, THREADS_SC, 0, stream>>>(dst, cnt);
        {
            int blocks = (BPAD * 64 + 255) / 256;  // one wave per bucket
            gin_scan<<<blocks, 256, 0, stream>>>(cnt, tot);
        }
        gin_scatter_bins<<<NB, THREADS_SC, 0, stream>>>(src, dst, cnt, bins);
        gin_reduce_mlp<<<NBUCKET, 256, 0, stream>>>(bins, tot, x, eps,
                                                    w1, b1, w2, b2, w3, b3, out);
    } else {
        // fallback: global-atomic path
        float* agg = (ws_size >= (size_t)N_NODES * sizeof(float)) ? (float*)d_ws : out;
        {
            int blocks = (N_NODES + 255) / 256;
            gin_zero_kernel<<<blocks, 256, 0, stream>>>(agg, N_NODES);
        }
        {
            int quads = N_EDGES / 4;
            int blocks = (quads + 255) / 256;
            gin_scatter_kernel<<<blocks, 256, 0, stream>>>(x, src, dst, agg);
        }
        {
            int blocks = (N_NODES + 255) / 256;
            gin_mlp_kernel<<<blocks, 256, 0, stream>>>(x, agg, eps, w1, b1, w2, b2,
                                                       w3, b3, out);
        }
    }
}

// Round 4
// 410.529 us; speedup vs baseline: 3.8386x; 1.6955x over previous
//
#include <hip/hip_runtime.h>

#define N_NODES 1000000
#define N_EDGES 32000000

// ---- binning configuration -------------------------------------------------
#define NB        256       // blocks for count/scatter phases
#define TSC       1024      // threads per count/scatter block
#define EPB       125000    // edges per block (NB * EPB == N_EDGES)
#define QPB       31250     // int4 quads per block
#define NBKT      245       // buckets of 4096 nodes; bucket = dst >> 12
#define BKT_PAD   256
#define CAP       135168    // per-bucket capacity (mean 131072 + 11 sigma), mult of 32
#define RING      96        // LDS ring entries per bucket (mult of 32)

#define BINS_ELEMS  ((size_t)NBKT * CAP)                       // 33,116,160 u32
#define CNT_ELEMS   ((size_t)NB * BKT_PAD)                     // 65,536 u32
#define WS_NEEDED   ((BINS_ELEMS + CNT_ELEMS + BKT_PAD) * 4)   // ~132.7 MB

// ---------------------------------------------------------------------------
// P1: per-(block,bucket) histogram of dst.
// ---------------------------------------------------------------------------
__global__ __launch_bounds__(TSC) void gin_count(const int* __restrict__ dst,
                                                 unsigned* __restrict__ cnt) {
    __shared__ unsigned h[BKT_PAD];
    int tid = threadIdx.x;
    if (tid < BKT_PAD) h[tid] = 0u;
    __syncthreads();
    int k = blockIdx.x;
    const int4* q = reinterpret_cast<const int4*>(dst) + (size_t)k * QPB;
    for (int i = tid; i < QPB; i += TSC) {
        int4 d = q[i];
        atomicAdd(&h[d.x >> 12], 1u);
        atomicAdd(&h[d.y >> 12], 1u);
        atomicAdd(&h[d.z >> 12], 1u);
        atomicAdd(&h[d.w >> 12], 1u);
    }
    __syncthreads();
    if (tid < BKT_PAD) cnt[(size_t)k * BKT_PAD + tid] = h[tid];
}

// ---------------------------------------------------------------------------
// P2: one wave per bucket: exclusive scan of cnt[k][b] over k, total -> tot[b].
// ---------------------------------------------------------------------------
__global__ void gin_scan(unsigned* __restrict__ cnt, unsigned* __restrict__ tot) {
    int gtid = blockIdx.x * blockDim.x + threadIdx.x;
    int b = gtid >> 6;          // wave id = bucket
    int lane = gtid & 63;
    if (b >= BKT_PAD) return;
    unsigned running = 0;
    for (int base = 0; base < NB; base += 64) {
        int idx = base + lane;
        unsigned v = (idx < NB) ? cnt[(size_t)idx * BKT_PAD + b] : 0u;
        unsigned s = v;
        for (int d = 1; d < 64; d <<= 1) {
            unsigned u = __shfl_up(s, d);
            if (lane >= d) s += u;
        }
        unsigned excl = s - v;
        if (idx < NB) cnt[(size_t)idx * BKT_PAD + b] = running + excl;
        running += __shfl(s, 63);
    }
    if (lane == 0) tot[b] = running;
}

// ---------------------------------------------------------------------------
// P3: LDS ring-staged scatter into dense per-bucket bins.
// Entry: (dst & 4095) << 20 | src   (12 + 20 = 32 bits exactly).
// Complete 32-entry chunks are flushed as 128B contiguous store bursts.
// ---------------------------------------------------------------------------
__global__ __launch_bounds__(TSC) void gin_scatter_bins(const int* __restrict__ src,
                                                        const int* __restrict__ dst,
                                                        const unsigned* __restrict__ cnt,
                                                        unsigned* __restrict__ bins) {
    __shared__ unsigned stage[BKT_PAD][RING];   // 96 KB
    __shared__ unsigned stot[BKT_PAD];          // staged total (monotonic)
    __shared__ unsigned sflt[BKT_PAD];          // flushed count
    __shared__ unsigned sbase[BKT_PAD];         // global start within bucket

    int tid = threadIdx.x;
    int k = blockIdx.x;
    if (tid < BKT_PAD) {
        stot[tid] = 0u;
        sflt[tid] = 0u;
        sbase[tid] = cnt[(size_t)k * BKT_PAD + tid];
    }
    __syncthreads();

    const int4* qs = reinterpret_cast<const int4*>(src) + (size_t)k * QPB;
    const int4* qd = reinterpret_cast<const int4*>(dst) + (size_t)k * QPB;

    for (int t0 = 0; t0 < QPB; t0 += TSC) {
        int i = t0 + tid;
        if (i < QPB) {
            int4 s4 = qs[i];
            int4 d4 = qd[i];
#define PUT(ss, dd) do {                                                     \
            unsigned b_ = (unsigned)(dd) >> 12;                              \
            unsigned p_ = atomicAdd(&stot[b_], 1u);                          \
            stage[b_][p_ % RING] =                                           \
                (((unsigned)(dd) & 4095u) << 20) | (unsigned)(ss);           \
        } while (0)
            PUT(s4.x, d4.x);
            PUT(s4.y, d4.y);
            PUT(s4.z, d4.z);
            PUT(s4.w, d4.w);
#undef PUT
        }
        __syncthreads();
        // flush complete 32-entry chunks; thread t owns bucket t
        if (tid < BKT_PAD) {
            unsigned b = (unsigned)tid;
            unsigned T = stot[b];
            unsigned F = sflt[b];
            if (F + 32 <= T) {
                unsigned gbase = sbase[b];
                unsigned* gout = bins + (size_t)b * CAP;
                while (F + 32 <= T) {
                    unsigned r = F % RING;
                    unsigned gp = gbase + F;
                    if (gp + 32 <= CAP) {
#pragma unroll
                        for (int c = 0; c < 32; ++c) gout[gp + c] = stage[b][r + c];
                    }
                    F += 32;
                }
                sflt[b] = F;
            }
        }
        __syncthreads();
    }
    // final flush of partial chunks
    if (tid < BKT_PAD) {
        unsigned b = (unsigned)tid;
        unsigned T = stot[b];
        unsigned F = sflt[b];
        unsigned gbase = sbase[b];
        unsigned* gout = bins + (size_t)b * CAP;
        for (; F < T; ++F) {
            unsigned gp = gbase + F;
            if (gp < CAP) gout[gp] = stage[b][F % RING];
        }
    }
}

// ---------------------------------------------------------------------------
// P4: per-bucket reduce (4096-node LDS acc) + fused MLP + store.
// ---------------------------------------------------------------------------
__global__ __launch_bounds__(1024) void gin_reduce_mlp(const unsigned* __restrict__ bins,
                               const unsigned* __restrict__ tot,
                               const float* __restrict__ x,
                               const float* __restrict__ eps,
                               const float* __restrict__ w1,
                               const float* __restrict__ b1,
                               const float* __restrict__ w2,
                               const float* __restrict__ b2,
                               const float* __restrict__ w3,
                               const float* __restrict__ b3,
                               float* __restrict__ out) {
    __shared__ float acc[4096];
    int tid = threadIdx.x;
    int b = blockIdx.x;                    // 0..NBKT-1
    for (int i = tid; i < 4096; i += 1024) acc[i] = 0.0f;
    __syncthreads();

    unsigned n = tot[b];
    if (n > CAP) n = CAP;
    const unsigned* bb = bins + (size_t)b * CAP;
    const uint4* bb4 = reinterpret_cast<const uint4*>(bb);
    unsigned nq = n >> 2;
    for (unsigned i = tid; i < nq; i += 1024) {
        uint4 e = bb4[i];
        atomicAdd(&acc[e.x >> 20], x[e.x & 0xFFFFFu]);
        atomicAdd(&acc[e.y >> 20], x[e.y & 0xFFFFFu]);
        atomicAdd(&acc[e.z >> 20], x[e.z & 0xFFFFFu]);
        atomicAdd(&acc[e.w >> 20], x[e.w & 0xFFFFFu]);
    }
    for (unsigned i = (nq << 2) + tid; i < n; i += 1024) {
        unsigned e = bb[i];
        atomicAdd(&acc[e >> 20], x[e & 0xFFFFFu]);
    }
    __syncthreads();

    float epsv = 1.0f + eps[0];
    for (int j = tid; j < 4096; j += 1024) {
        int node = (b << 12) + j;
        if (node >= N_NODES) break;
        float h0 = epsv * x[node] + acc[j];

        float h1[20];
#pragma unroll
        for (int jj = 0; jj < 20; ++jj)
            h1[jj] = fmaxf(fmaf(h0, w1[jj], b1[jj]), 0.0f);

        float o = b3[0];
#pragma unroll
        for (int kk = 0; kk < 20; ++kk) {
            float a = b2[kk];
#pragma unroll
            for (int jj = 0; jj < 20; ++jj)
                a = fmaf(h1[jj], w2[jj * 20 + kk], a);
            o = fmaf(fmaxf(a, 0.0f), w3[kk], o);
        }
        out[node] = o;
    }
}

// ---------------------------------------------------------------------------
// Fallback path (round-1 kernels) if ws is too small for binning.
// ---------------------------------------------------------------------------
__global__ void gin_zero_kernel(float* __restrict__ agg, int n) {
    int i = blockIdx.x * blockDim.x + threadIdx.x;
    if (i < n) agg[i] = 0.0f;
}

__global__ void gin_scatter_kernel(const float* __restrict__ x,
                                   const int* __restrict__ src,
                                   const int* __restrict__ dst,
                                   float* __restrict__ agg) {
    int q = blockIdx.x * blockDim.x + threadIdx.x;
    int e = q * 4;
    if (e + 3 < N_EDGES) {
        int4 s = *reinterpret_cast<const int4*>(src + e);
        int4 d = *reinterpret_cast<const int4*>(dst + e);
        atomicAdd(&agg[d.x], x[s.x]);
        atomicAdd(&agg[d.y], x[s.y]);
        atomicAdd(&agg[d.z], x[s.z]);
        atomicAdd(&agg[d.w], x[s.w]);
    } else if (e < N_EDGES) {
        for (; e < N_EDGES; ++e) atomicAdd(&agg[dst[e]], x[src[e]]);
    }
}

__global__ void gin_mlp_kernel(const float* __restrict__ x,
                               const float* __restrict__ agg,
                               const float* __restrict__ eps,
                               const float* __restrict__ w1,
                               const float* __restrict__ b1,
                               const float* __restrict__ w2,
                               const float* __restrict__ b2,
                               const float* __restrict__ w3,
                               const float* __restrict__ b3,
                               float* __restrict__ out) {
    int i = blockIdx.x * blockDim.x + threadIdx.x;
    if (i >= N_NODES) return;
    float h0 = (1.0f + eps[0]) * x[i] + agg[i];
    float h1[20];
#pragma unroll
    for (int j = 0; j < 20; ++j) h1[j] = fmaxf(fmaf(h0, w1[j], b1[j]), 0.0f);
    float o = b3[0];
#pragma unroll
    for (int k = 0; k < 20; ++k) {
        float a = b2[k];
#pragma unroll
        for (int j = 0; j < 20; ++j) a = fmaf(h1[j], w2[j * 20 + k], a);
        o = fmaf(fmaxf(a, 0.0f), w3[k], o);
    }
    out[i] = o;
}

// ---------------------------------------------------------------------------
extern "C" void kernel_launch(void* const* d_in, const int* in_sizes, int n_in,
                              void* d_out, int out_size, void* d_ws, size_t ws_size,
                              hipStream_t stream) {
    const float* x    = (const float*)d_in[0];
    const int*   ei   = (const int*)  d_in[1];
    const float* eps  = (const float*)d_in[2];
    const float* w1   = (const float*)d_in[3];
    const float* b1   = (const float*)d_in[4];
    const float* w2   = (const float*)d_in[5];
    const float* b2   = (const float*)d_in[6];
    const float* w3   = (const float*)d_in[7];
    const float* b3   = (const float*)d_in[8];
    float* out = (float*)d_out;

    const int* src = ei;
    const int* dst = ei + N_EDGES;

    if (ws_size >= WS_NEEDED) {
        unsigned* bins = (unsigned*)d_ws;
        unsigned* cnt  = bins + BINS_ELEMS;
        unsigned* tot  = cnt + CNT_ELEMS;

        gin_count<<<NB, TSC, 0, stream>>>(dst, cnt);
        {
            int blocks = (BKT_PAD * 64 + 255) / 256;  // one wave per bucket
            gin_scan<<<blocks, 256, 0, stream>>>(cnt, tot);
        }
        gin_scatter_bins<<<NB, TSC, 0, stream>>>(src, dst, cnt, bins);
        gin_reduce_mlp<<<NBKT, 1024, 0, stream>>>(bins, tot, x, eps,
                                                  w1, b1, w2, b2, w3, b3, out);
    } else {
        // fallback: global-atomic path
        float* agg = (ws_size >= (size_t)N_NODES * sizeof(float)) ? (float*)d_ws : out;
        {
            int blocks = (N_NODES + 255) / 256;
            gin_zero_kernel<<<blocks, 256, 0, stream>>>(agg, N_NODES);
        }
        {
            int quads = N_EDGES / 4;
            int blocks = (quads + 255) / 256;
            gin_scatter_kernel<<<blocks, 256, 0, stream>>>(x, src, dst, agg);
        }
        {
            int blocks = (N_NODES + 255) / 256;
            gin_mlp_kernel<<<blocks, 256, 0, stream>>>(x, agg, eps, w1, b1, w2, b2,
                                                       w3, b3, out);
        }
    }
}

// Round 5
// 408.584 us; speedup vs baseline: 3.8568x; 1.0048x over previous
//
#include <hip/hip_runtime.h>

#define N_NODES 1000000
#define N_EDGES 32000000

// ---- binning configuration -------------------------------------------------
#define NB        256       // blocks for count/scatter phases
#define TSC       1024      // threads per count/scatter block
#define EPB       125000    // edges per block (NB * EPB == N_EDGES)
#define QPB       31250     // int4 quads per block
#define NBKT      245       // buckets of 4096 nodes; bucket = dst >> 12
#define BKT_PAD   256
#define CAP       135168    // per-bucket capacity (mean 130612 + margin), mult of 32
#define RING      96        // LDS ring entries per bucket (mult of 32)

#define BINS_ELEMS  ((size_t)NBKT * CAP)                       // 33,116,160 u32
#define CNT_ELEMS   ((size_t)NB * BKT_PAD)                     // 65,536 u32
#define PAGG_ELEMS  ((size_t)NBKT * 2 * 4096)                  // 2,007,040 f32
#define WS_NEEDED   ((BINS_ELEMS + CNT_ELEMS + BKT_PAD + PAGG_ELEMS) * 4)  // ~140.8 MB

// ---------------------------------------------------------------------------
// P1: per-(block,bucket) histogram of dst.
// ---------------------------------------------------------------------------
__global__ __launch_bounds__(TSC) void gin_count(const int* __restrict__ dst,
                                                 unsigned* __restrict__ cnt) {
    __shared__ unsigned h[BKT_PAD];
    int tid = threadIdx.x;
    if (tid < BKT_PAD) h[tid] = 0u;
    __syncthreads();
    int k = blockIdx.x;
    const int4* q = reinterpret_cast<const int4*>(dst) + (size_t)k * QPB;
    for (int i = tid; i < QPB; i += TSC) {
        int4 d = q[i];
        atomicAdd(&h[d.x >> 12], 1u);
        atomicAdd(&h[d.y >> 12], 1u);
        atomicAdd(&h[d.z >> 12], 1u);
        atomicAdd(&h[d.w >> 12], 1u);
    }
    __syncthreads();
    if (tid < BKT_PAD) cnt[(size_t)k * BKT_PAD + tid] = h[tid];
}

// ---------------------------------------------------------------------------
// P2: one wave per bucket: exclusive scan of cnt[k][b] over k, total -> tot[b].
// ---------------------------------------------------------------------------
__global__ void gin_scan(unsigned* __restrict__ cnt, unsigned* __restrict__ tot) {
    int gtid = blockIdx.x * blockDim.x + threadIdx.x;
    int b = gtid >> 6;          // wave id = bucket
    int lane = gtid & 63;
    if (b >= BKT_PAD) return;
    unsigned running = 0;
    for (int base = 0; base < NB; base += 64) {
        int idx = base + lane;
        unsigned v = (idx < NB) ? cnt[(size_t)idx * BKT_PAD + b] : 0u;
        unsigned s = v;
        for (int d = 1; d < 64; d <<= 1) {
            unsigned u = __shfl_up(s, d);
            if (lane >= d) s += u;
        }
        unsigned excl = s - v;
        if (idx < NB) cnt[(size_t)idx * BKT_PAD + b] = running + excl;
        running += __shfl(s, 63);
    }
    if (lane == 0) tot[b] = running;
}

// ---------------------------------------------------------------------------
// P3: LDS ring-staged scatter into dense per-bucket bins.
// Entry: (dst & 4095) << 20 | src   (12 + 20 = 32 bits exactly).
// Complete 32-entry chunks are flushed as 128B contiguous store bursts.
// ---------------------------------------------------------------------------
__global__ __launch_bounds__(TSC) void gin_scatter_bins(const int* __restrict__ src,
                                                        const int* __restrict__ dst,
                                                        const unsigned* __restrict__ cnt,
                                                        unsigned* __restrict__ bins) {
    __shared__ unsigned stage[BKT_PAD][RING];   // 96 KB
    __shared__ unsigned stot[BKT_PAD];          // staged total (monotonic)
    __shared__ unsigned sflt[BKT_PAD];          // flushed count
    __shared__ unsigned sbase[BKT_PAD];         // global start within bucket

    int tid = threadIdx.x;
    int k = blockIdx.x;
    if (tid < BKT_PAD) {
        stot[tid] = 0u;
        sflt[tid] = 0u;
        sbase[tid] = cnt[(size_t)k * BKT_PAD + tid];
    }
    __syncthreads();

    const int4* qs = reinterpret_cast<const int4*>(src) + (size_t)k * QPB;
    const int4* qd = reinterpret_cast<const int4*>(dst) + (size_t)k * QPB;

    for (int t0 = 0; t0 < QPB; t0 += TSC) {
        int i = t0 + tid;
        if (i < QPB) {
            int4 s4 = qs[i];
            int4 d4 = qd[i];
#define PUT(ss, dd) do {                                                     \
            unsigned b_ = (unsigned)(dd) >> 12;                              \
            unsigned p_ = atomicAdd(&stot[b_], 1u);                          \
            stage[b_][p_ % RING] =                                           \
                (((unsigned)(dd) & 4095u) << 20) | (unsigned)(ss);           \
        } while (0)
            PUT(s4.x, d4.x);
            PUT(s4.y, d4.y);
            PUT(s4.z, d4.z);
            PUT(s4.w, d4.w);
#undef PUT
        }
        __syncthreads();
        // flush complete 32-entry chunks; thread t owns bucket t
        if (tid < BKT_PAD) {
            unsigned b = (unsigned)tid;
            unsigned T = stot[b];
            unsigned F = sflt[b];
            if (F + 32 <= T) {
                unsigned gbase = sbase[b];
                unsigned* gout = bins + (size_t)b * CAP;
                while (F + 32 <= T) {
                    unsigned r = F % RING;
                    unsigned gp = gbase + F;
                    if (gp + 32 <= CAP) {
#pragma unroll
                        for (int c = 0; c < 32; ++c) gout[gp + c] = stage[b][r + c];
                    }
                    F += 32;
                }
                sflt[b] = F;
            }
        }
        __syncthreads();
    }
    // final flush of partial chunks
    if (tid < BKT_PAD) {
        unsigned b = (unsigned)tid;
        unsigned T = stot[b];
        unsigned F = sflt[b];
        unsigned gbase = sbase[b];
        unsigned* gout = bins + (size_t)b * CAP;
        for (; F < T; ++F) {
            unsigned gp = gbase + F;
            if (gp < CAP) gout[gp] = stage[b][F % RING];
        }
    }
}

// ---------------------------------------------------------------------------
// P4: per-(bucket,half) reduce into LDS acc, dump partial agg to ws.
// Two blocks per bucket -> 2 blocks/CU -> ~2x wave parallelism.
// ---------------------------------------------------------------------------
__global__ __launch_bounds__(1024) void gin_reduce(const unsigned* __restrict__ bins,
                                                   const unsigned* __restrict__ tot,
                                                   const float* __restrict__ x,
                                                   float* __restrict__ pagg) {
    __shared__ float acc[4096];
    int tid = threadIdx.x;
    int blk = blockIdx.x;            // 0..2*NBKT-1
    int b = blk >> 1;                // bucket
    int h = blk & 1;                 // half
    for (int i = tid; i < 4096; i += 1024) acc[i] = 0.0f;
    __syncthreads();

    unsigned n = tot[b];
    if (n > CAP) n = CAP;
    const unsigned* bb = bins + (size_t)b * CAP;
    const uint4* bb4 = reinterpret_cast<const uint4*>(bb);
    unsigned nq = n >> 2;
    unsigned q_lo = h ? (nq >> 1) : 0;
    unsigned q_hi = h ? nq : (nq >> 1);
    for (unsigned i = q_lo + tid; i < q_hi; i += 1024) {
        uint4 e = bb4[i];
        atomicAdd(&acc[e.x >> 20], x[e.x & 0xFFFFFu]);
        atomicAdd(&acc[e.y >> 20], x[e.y & 0xFFFFFu]);
        atomicAdd(&acc[e.z >> 20], x[e.z & 0xFFFFFu]);
        atomicAdd(&acc[e.w >> 20], x[e.w & 0xFFFFFu]);
    }
    if (h) {  // tail entries (n not multiple of 4)
        for (unsigned i = (nq << 2) + tid; i < n; i += 1024) {
            unsigned e = bb[i];
            atomicAdd(&acc[e >> 20], x[e & 0xFFFFFu]);
        }
    }
    __syncthreads();

    float* po = pagg + (size_t)blk * 4096;
    for (int i = tid; i < 4096; i += 1024) po[i] = acc[i];
}

// ---------------------------------------------------------------------------
// P5: combine the two partials + fused MLP + store.
// ---------------------------------------------------------------------------
__global__ __launch_bounds__(512) void gin_combine_mlp(const float* __restrict__ pagg,
                               const float* __restrict__ x,
                               const float* __restrict__ eps,
                               const float* __restrict__ w1,
                               const float* __restrict__ b1,
                               const float* __restrict__ w2,
                               const float* __restrict__ b2,
                               const float* __restrict__ w3,
                               const float* __restrict__ b3,
                               float* __restrict__ out) {
    int i = blockIdx.x * blockDim.x + threadIdx.x;
    if (i >= N_NODES) return;
    int b = i >> 12;
    int j = i & 4095;
    float agg = pagg[(size_t)(b * 2) * 4096 + j] + pagg[(size_t)(b * 2 + 1) * 4096 + j];
    float h0 = (1.0f + eps[0]) * x[i] + agg;

    float h1[20];
#pragma unroll
    for (int jj = 0; jj < 20; ++jj)
        h1[jj] = fmaxf(fmaf(h0, w1[jj], b1[jj]), 0.0f);

    float o = b3[0];
#pragma unroll
    for (int kk = 0; kk < 20; ++kk) {
        float a = b2[kk];
#pragma unroll
        for (int jj = 0; jj < 20; ++jj)
            a = fmaf(h1[jj], w2[jj * 20 + kk], a);
        o = fmaf(fmaxf(a, 0.0f), w3[kk], o);
    }
    out[i] = o;
}

// ---------------------------------------------------------------------------
// Fallback path (round-1 kernels) if ws is too small for binning.
// ---------------------------------------------------------------------------
__global__ void gin_zero_kernel(float* __restrict__ agg, int n) {
    int i = blockIdx.x * blockDim.x + threadIdx.x;
    if (i < n) agg[i] = 0.0f;
}

__global__ void gin_scatter_kernel(const float* __restrict__ x,
                                   const int* __restrict__ src,
                                   const int* __restrict__ dst,
                                   float* __restrict__ agg) {
    int q = blockIdx.x * blockDim.x + threadIdx.x;
    int e = q * 4;
    if (e + 3 < N_EDGES) {
        int4 s = *reinterpret_cast<const int4*>(src + e);
        int4 d = *reinterpret_cast<const int4*>(dst + e);
        atomicAdd(&agg[d.x], x[s.x]);
        atomicAdd(&agg[d.y], x[s.y]);
        atomicAdd(&agg[d.z], x[s.z]);
        atomicAdd(&agg[d.w], x[s.w]);
    } else if (e < N_EDGES) {
        for (; e < N_EDGES; ++e) atomicAdd(&agg[dst[e]], x[src[e]]);
    }
}

__global__ void gin_mlp_kernel(const float* __restrict__ x,
                               const float* __restrict__ agg,
                               const float* __restrict__ eps,
                               const float* __restrict__ w1,
                               const float* __restrict__ b1,
                               const float* __restrict__ w2,
                               const float* __restrict__ b2,
                               const float* __restrict__ w3,
                               const float* __restrict__ b3,
                               float* __restrict__ out) {
    int i = blockIdx.x * blockDim.x + threadIdx.x;
    if (i >= N_NODES) return;
    float h0 = (1.0f + eps[0]) * x[i] + agg[i];
    float h1[20];
#pragma unroll
    for (int j = 0; j < 20; ++j) h1[j] = fmaxf(fmaf(h0, w1[j], b1[j]), 0.0f);
    float o = b3[0];
#pragma unroll
    for (int k = 0; k < 20; ++k) {
        float a = b2[k];
#pragma unroll
        for (int j = 0; j < 20; ++j) a = fmaf(h1[j], w2[j * 20 + k], a);
        o = fmaf(fmaxf(a, 0.0f), w3[k], o);
    }
    out[i] = o;
}

// ---------------------------------------------------------------------------
extern "C" void kernel_launch(void* const* d_in, const int* in_sizes, int n_in,
                              void* d_out, int out_size, void* d_ws, size_t ws_size,
                              hipStream_t stream) {
    const float* x    = (const float*)d_in[0];
    const int*   ei   = (const int*)  d_in[1];
    const float* eps  = (const float*)d_in[2];
    const float* w1   = (const float*)d_in[3];
    const float* b1   = (const float*)d_in[4];
    const float* w2   = (const float*)d_in[5];
    const float* b2   = (const float*)d_in[6];
    const float* w3   = (const float*)d_in[7];
    const float* b3   = (const float*)d_in[8];
    float* out = (float*)d_out;

    const int* src = ei;
    const int* dst = ei + N_EDGES;

    if (ws_size >= WS_NEEDED) {
        unsigned* bins = (unsigned*)d_ws;
        unsigned* cnt  = bins + BINS_ELEMS;
        unsigned* tot  = cnt + CNT_ELEMS;
        float*    pagg = (float*)(tot + BKT_PAD);

        gin_count<<<NB, TSC, 0, stream>>>(dst, cnt);
        {
            int blocks = (BKT_PAD * 64 + 255) / 256;  // one wave per bucket
            gin_scan<<<blocks, 256, 0, stream>>>(cnt, tot);
        }
        gin_scatter_bins<<<NB, TSC, 0, stream>>>(src, dst, cnt, bins);
        gin_reduce<<<NBKT * 2, 1024, 0, stream>>>(bins, tot, x, pagg);
        gin_combine_mlp<<<(N_NODES + 511) / 512, 512, 0, stream>>>(pagg, x, eps,
                                                 w1, b1, w2, b2, w3, b3, out);
    } else {
        // fallback: global-atomic path
        float* agg = (ws_size >= (size_t)N_NODES * sizeof(float)) ? (float*)d_ws : out;
        {
            int blocks = (N_NODES + 255) / 256;
            gin_zero_kernel<<<blocks, 256, 0, stream>>>(agg, N_NODES);
        }
        {
            int quads = N_EDGES / 4;
            int blocks = (quads + 255) / 256;
            gin_scatter_kernel<<<blocks, 256, 0, stream>>>(x, src, dst, agg);
        }
        {
            int blocks = (N_NODES + 255) / 256;
            gin_mlp_kernel<<<blocks, 256, 0, stream>>>(x, agg, eps, w1, b1, w2, b2,
                                                       w3, b3, out);
        }
    }
}